// Round 5
// baseline (392.698 us; speedup 1.0000x reference)
//
#include <hip/hip_runtime.h>

#define NPTS  65536
#define KNB   32
#define KPn   15
#define CIN   64
#define COUT  128
#define MPTS  32            // points per block (2 MFMA M-tiles)
#define THREADS 512
#define WSTRIDE 968         // wl row stride in bf16 elements (960 + 8 pad)
#define MAXE  512           // active-entry list capacity (~62 expected)
#define NTILE 8             // 128 cols / 16
#define KSTEPS 30           // 960 / 32

typedef __attribute__((ext_vector_type(8))) short short8;
typedef __attribute__((ext_vector_type(4))) float f32x4;

__device__ __forceinline__ unsigned int f2bf(float f) {
    union { float f; unsigned int i; } v; v.f = f;
    return (v.i + 0x7fffu + ((v.i >> 16) & 1u)) >> 16;   // RNE
}

// ---- prep: weights [960][128] f32 -> wTf in MFMA B-fragment order ----
// wTf[((t*30 + ks)*64 + lane)*8 + j] = W[ks*32 + (lane>>4)*8 + j][t*16 + (lane&15)]
__global__ void wtrans_kernel(const float* __restrict__ w,
                              unsigned short* __restrict__ wTf) {
    const int i = blockIdx.x * 256 + threadIdx.x;
    if (i < NTILE * KSTEPS * 64) {
        const int lane = i & 63;
        const int ks   = (i >> 6) % KSTEPS;
        const int t    = i / (64 * KSTEPS);
        const int kbase = ks * 32 + (lane >> 4) * 8;
        const int n     = t * 16 + (lane & 15);
        unsigned short frag[8];
        #pragma unroll
        for (int j = 0; j < 8; ++j)
            frag[j] = (unsigned short)f2bf(w[(size_t)(kbase + j) * COUT + n]);
        *(short8*)(wTf + (size_t)i * 8) = *(short8*)frag;
    }
}

__global__ __launch_bounds__(THREADS, 4) void kpconv_kernel(
    const float* __restrict__ pos,         // [N,3] f32
    const float* __restrict__ feats,       // [N,64] f32
    const float* __restrict__ kpts,        // [15,3] f32
    const unsigned short* __restrict__ wTf,// fragment-packed bf16 weights
    const int*   __restrict__ neighbors,   // [N,32] int32
    float*       __restrict__ out)         // [N,128] f32
{
    __shared__ unsigned short wl[MPTS * WSTRIDE]; // 61952 B, bf16 weighted feats
    __shared__ int   nbidx[MPTS * KNB];           // 4 KB
    __shared__ int   eid[MAXE];                   // 2 KB  (s<<4 | k), s = p*32+j
    __shared__ float eval_[MAXE];                 // 2 KB
    __shared__ float cposf[MPTS * 3];
    __shared__ float kpfl[KPn * 3];
    __shared__ int   ecount;

    const int tid = threadIdx.x;
    const int n0  = blockIdx.x * MPTS;

    // ---- init ----
    if (tid < MPTS * 3) cposf[tid] = pos[(size_t)n0 * 3 + tid];
    if (tid < KPn * 3)  kpfl[tid]  = kpts[tid];
    if (tid == 0) ecount = 0;
    __syncthreads();

    // ---- stage 1a: influences for all 1024 (p,j) slots; push active entries ----
    for (int s = tid; s < MPTS * KNB; s += THREADS) {
        const int p  = s >> 5;
        const int nb = neighbors[(size_t)n0 * KNB + s];
        nbidx[s] = nb;
        const float rx = pos[(size_t)nb * 3 + 0] - cposf[p * 3 + 0];
        const float ry = pos[(size_t)nb * 3 + 1] - cposf[p * 3 + 1];
        const float rz = pos[(size_t)nb * 3 + 2] - cposf[p * 3 + 2];
        #pragma unroll
        for (int k = 0; k < KPn; ++k) {
            const float dx = rx - kpfl[k * 3 + 0];
            const float dy = ry - kpfl[k * 3 + 1];
            const float dz = rz - kpfl[k * 3 + 2];
            const float d2 = dx * dx + dy * dy + dz * dz;
            if (d2 < 0.01f) {                       // dist < sigma
                const float w = 1.0f - 10.0f * sqrtf(d2);
                const int idx = atomicAdd(&ecount, 1);
                if (idx < MAXE) { eid[idx] = (s << 4) | k; eval_[idx] = w; }
            }
        }
    }
    __syncthreads();

    // ---- stage 1b: ownership accumulation. thread t<480 owns (p,k); scans the
    // entry list, accumulates 64 channels in registers, writes bf16 row once ----
    if (tid < MPTS * KPn) {
        const int p = tid / KPn;
        const int k = tid - p * KPn;
        f32x4 acc4[16];
        #pragma unroll
        for (int c = 0; c < 16; ++c) acc4[c] = (f32x4){0.f, 0.f, 0.f, 0.f};

        const int E = min(ecount, MAXE);
        for (int e = 0; e < E; ++e) {
            const int id = eid[e];                 // (p<<9) | (j<<4) | k
            if ((id & 15) == k && (id >> 9) == p) {
                const float w = eval_[e];
                const float* fr = feats + (size_t)nbidx[id >> 4] * CIN;
                #pragma unroll 8
                for (int c = 0; c < 16; ++c) {
                    const float4 f = *(const float4*)(fr + c * 4);
                    acc4[c].x += w * f.x; acc4[c].y += w * f.y;
                    acc4[c].z += w * f.z; acc4[c].w += w * f.w;
                }
            }
        }
        // pack -> bf16, chunk-rotated writes (8 chunks of 8 channels)
        unsigned short* row = wl + p * WSTRIDE + k * 64;
        #pragma unroll
        for (int cc = 0; cc < 8; ++cc) {
            const int c = (tid + cc) & 7;
            const f32x4 lo = acc4[c * 2], hi = acc4[c * 2 + 1];
            uint4 u;
            u.x = f2bf(lo.x) | (f2bf(lo.y) << 16);
            u.y = f2bf(lo.z) | (f2bf(lo.w) << 16);
            u.z = f2bf(hi.x) | (f2bf(hi.y) << 16);
            u.w = f2bf(hi.z) | (f2bf(hi.w) << 16);
            *(uint4*)(row + c * 8) = u;
        }
    }
    __syncthreads();

    // ---- stage 2: out[32][128] = wl[32][960] @ W[960][128] via MFMA bf16 ----
    // wave w owns N-tile w (cols w*16..+15); B loaded once, used for 2 M-tiles.
    {
        const int wave = tid >> 6;
        const int lane = tid & 63;
        const int m    = lane & 15;
        const int q    = lane >> 4;

        f32x4 acc0 = {0.f, 0.f, 0.f, 0.f};   // M-tile 0 (points 0..15)
        f32x4 acc1 = {0.f, 0.f, 0.f, 0.f};   // M-tile 1 (points 16..31)

        const unsigned short* a0p = wl + m * WSTRIDE + q * 8;
        const unsigned short* a1p = a0p + 16 * WSTRIDE;
        const short8* bp = (const short8*)wTf + (size_t)wave * KSTEPS * 64 + lane;

        #pragma unroll 3
        for (int ks = 0; ks < KSTEPS; ++ks, a0p += 32, a1p += 32, bp += 64) {
            const short8 a0 = *(const short8*)a0p;
            const short8 a1 = *(const short8*)a1p;
            const short8 b  = *bp;
            acc0 = __builtin_amdgcn_mfma_f32_16x16x32_bf16(a0, b, acc0, 0, 0, 0);
            acc1 = __builtin_amdgcn_mfma_f32_16x16x32_bf16(a1, b, acc1, 0, 0, 0);
        }

        // C/D layout: col = lane&15, row = q*4 + reg
        const int c = wave * 16 + m;
        #pragma unroll
        for (int r = 0; r < 4; ++r) {
            out[(size_t)(n0 + q * 4 + r) * COUT + c]      = acc0[r];
            out[(size_t)(n0 + 16 + q * 4 + r) * COUT + c] = acc1[r];
        }
    }
}

extern "C" void kernel_launch(void* const* d_in, const int* in_sizes, int n_in,
                              void* d_out, int out_size, void* d_ws, size_t ws_size,
                              hipStream_t stream) {
    const float* pos       = (const float*)d_in[0];
    const float* feats     = (const float*)d_in[1];
    const float* kpts      = (const float*)d_in[2];
    const float* weights   = (const float*)d_in[3];
    const int*   neighbors = (const int*)d_in[4];
    float*       out       = (float*)d_out;
    unsigned short* wTf    = (unsigned short*)d_ws;   // 8*30*64*8*2 = 245760 B

    wtrans_kernel<<<(NTILE * KSTEPS * 64 + 255) / 256, 256, 0, stream>>>(weights, wTf);
    kpconv_kernel<<<NPTS / MPTS, THREADS, 0, stream>>>(pos, feats, kpts, wTf, neighbors, out);
}

// Round 6
// 151.487 us; speedup vs baseline: 2.5923x; 2.5923x over previous
//
#include <hip/hip_runtime.h>

#define NPTS  65536
#define KNB   32
#define KPn   15
#define CIN   64
#define COUT  128
#define MPTS  16            // points per block (MFMA M)
#define THREADS 256
#define WSTRIDE 968         // wl row stride in bf16 elements (960 + 8 pad)
#define BCAP  32            // per-point active-entry bucket capacity (λ≈2)
#define NTILE 8             // 128 cols / 16
#define KSTEPS 30           // 960 / 32

typedef __attribute__((ext_vector_type(8))) short short8;
typedef __attribute__((ext_vector_type(4))) float f32x4;

__device__ __forceinline__ unsigned int f2bf(float f) {
    union { float f; unsigned int i; } v; v.f = f;
    return (v.i + 0x7fffu + ((v.i >> 16) & 1u)) >> 16;   // RNE
}

// ---- prep: pack weights into MFMA B-fragment order with permuted K ----
// flat K position f = ks*32 + q*8 + j  maps to original (kpk, channel):
//   cg = f/120, rem = f%120, kpk = rem/8, cw = rem&7, channel = cg*8+cw
// wTf element d = ((t*KSTEPS + ks)*64 + lane)*8 + j = W[kpk*64+cg*8+cw][t*16 + (lane&15)]
// One element per thread: writes fully coalesced, reads latency-hidden by 480 blocks.
__global__ void wtrans_kernel(const float* __restrict__ w,
                              unsigned short* __restrict__ wTf) {
    const int d = blockIdx.x * 256 + threadIdx.x;
    if (d < NTILE * KSTEPS * 64 * 8) {
        const int j    = d & 7;
        const int lane = (d >> 3) & 63;
        const int ks   = (d >> 9) % KSTEPS;
        const int t    = d / (KSTEPS * 512);
        const int f    = ks * 32 + (lane >> 4) * 8 + j;
        const int cg   = f / 120;
        const int rem  = f - cg * 120;
        const int kpk  = rem >> 3;
        const int cw   = rem & 7;
        const int orig = kpk * 64 + cg * 8 + cw;     // row in W[960][128]
        const int n    = t * 16 + (lane & 15);
        wTf[d] = (unsigned short)f2bf(w[(size_t)orig * COUT + n]);
    }
}

__global__ __launch_bounds__(THREADS, 4) void kpconv_kernel(
    const float* __restrict__ pos,         // [N,3] f32
    const float* __restrict__ feats,       // [N,64] f32
    const float* __restrict__ kpts,        // [15,3] f32
    const unsigned short* __restrict__ wTf,// fragment-packed bf16 weights
    const int*   __restrict__ neighbors,   // [N,32] int32
    float*       __restrict__ out)         // [N,128] f32
{
    __shared__ unsigned short wl[MPTS * WSTRIDE]; // 30976 B bf16 (permuted-K layout)
    __shared__ int   bcnt[MPTS];
    __shared__ int   bid[MPTS][BCAP];             // (nb << 4) | k
    __shared__ float bval[MPTS][BCAP];
    __shared__ float cposf[MPTS * 3];
    __shared__ float kpfl[KPn * 3];

    const int tid = threadIdx.x;
    const int n0  = blockIdx.x * MPTS;

    // ---- init ----
    if (tid < MPTS) bcnt[tid] = 0;
    if (tid < MPTS * 3) cposf[tid] = pos[(size_t)n0 * 3 + tid];
    if (tid < KPn * 3)  kpfl[tid]  = kpts[tid];
    __syncthreads();

    // ---- stage 1a: influences for all 512 (p,j) slots; bucket active entries ----
    for (int s = tid; s < MPTS * KNB; s += THREADS) {
        const int p  = s >> 5;
        const int nb = neighbors[(size_t)n0 * KNB + s];
        const float rx = pos[(size_t)nb * 3 + 0] - cposf[p * 3 + 0];
        const float ry = pos[(size_t)nb * 3 + 1] - cposf[p * 3 + 1];
        const float rz = pos[(size_t)nb * 3 + 2] - cposf[p * 3 + 2];
        #pragma unroll
        for (int k = 0; k < KPn; ++k) {
            const float dx = rx - kpfl[k * 3 + 0];
            const float dy = ry - kpfl[k * 3 + 1];
            const float dz = rz - kpfl[k * 3 + 2];
            const float d2 = dx * dx + dy * dy + dz * dz;
            if (d2 < 0.01f) {                       // dist < sigma
                const float w = 1.0f - 10.0f * sqrtf(d2);
                const int idx = atomicAdd(&bcnt[p], 1);
                if (idx < BCAP) { bid[p][idx] = (nb << 4) | k; bval[p][idx] = w; }
            }
        }
    }
    __syncthreads();

    // ---- stage 1b: ownership accumulation, 8 channels per work item ----
    // work item wi = p*128 + k*8 + cg (k==15 is a hole); acc[] statically indexed
    #pragma unroll
    for (int it = 0; it < 8; ++it) {
        const int wi = tid + it * THREADS;           // 0..2047
        const int cg = wi & 7;
        const int k  = (wi >> 3) & 15;
        const int p  = wi >> 7;
        if (k < KPn) {
            float a0=0.f,a1=0.f,a2=0.f,a3=0.f,a4=0.f,a5=0.f,a6=0.f,a7=0.f;
            const int cnt = min(bcnt[p], BCAP);
            for (int e = 0; e < cnt; ++e) {
                const int id = bid[p][e];
                if ((id & 15) == k) {
                    const float wv = bval[p][e];
                    const float* fr = feats + (size_t)(id >> 4) * CIN + cg * 8;
                    const float4 f0 = *(const float4*)fr;
                    const float4 f1 = *(const float4*)(fr + 4);
                    a0 += wv * f0.x; a1 += wv * f0.y; a2 += wv * f0.z; a3 += wv * f0.w;
                    a4 += wv * f1.x; a5 += wv * f1.y; a6 += wv * f1.z; a7 += wv * f1.w;
                }
            }
            uint4 u;
            u.x = f2bf(a0) | (f2bf(a1) << 16);
            u.y = f2bf(a2) | (f2bf(a3) << 16);
            u.z = f2bf(a4) | (f2bf(a5) << 16);
            u.w = f2bf(a6) | (f2bf(a7) << 16);
            // permuted-K flat position: cg*120 + k*8 (16B-aligned: cg*240 + k*16 bytes)
            *(uint4*)(wl + p * WSTRIDE + cg * 120 + k * 8) = u;
        }
    }
    __syncthreads();

    // ---- stage 2: out[16][128] = wl @ W via MFMA bf16 (permuted-K consistent) ----
    {
        const int wave = tid >> 6;
        const int lane = tid & 63;
        const int m    = lane & 15;
        const int q    = lane >> 4;

        f32x4 acc0 = {0.f, 0.f, 0.f, 0.f};
        f32x4 acc1 = {0.f, 0.f, 0.f, 0.f};

        const unsigned short* ap = wl + m * WSTRIDE + q * 8;
        const short8* bp0 = (const short8*)wTf + (size_t)(2 * wave) * KSTEPS * 64 + lane;
        const short8* bp1 = bp0 + (size_t)KSTEPS * 64;

        #pragma unroll 3
        for (int ks = 0; ks < KSTEPS; ++ks, ap += 32) {
            const short8 a  = *(const short8*)ap;
            const short8 b0 = bp0[ks * 64];
            const short8 b1 = bp1[ks * 64];
            acc0 = __builtin_amdgcn_mfma_f32_16x16x32_bf16(a, b0, acc0, 0, 0, 0);
            acc1 = __builtin_amdgcn_mfma_f32_16x16x32_bf16(a, b1, acc1, 0, 0, 0);
        }

        // C/D layout: col = lane&15, row = q*4 + reg
        const int nb0 = wave * 32;
        #pragma unroll
        for (int r = 0; r < 4; ++r) {
            const size_t row = (size_t)(n0 + q * 4 + r) * COUT;
            out[row + nb0 + m]      = acc0[r];
            out[row + nb0 + 16 + m] = acc1[r];
        }
    }
}

extern "C" void kernel_launch(void* const* d_in, const int* in_sizes, int n_in,
                              void* d_out, int out_size, void* d_ws, size_t ws_size,
                              hipStream_t stream) {
    const float* pos       = (const float*)d_in[0];
    const float* feats     = (const float*)d_in[1];
    const float* kpts      = (const float*)d_in[2];
    const float* weights   = (const float*)d_in[3];
    const int*   neighbors = (const int*)d_in[4];
    float*       out       = (float*)d_out;
    unsigned short* wTf    = (unsigned short*)d_ws;   // 8*30*64*8*2 = 245760 B

    wtrans_kernel<<<(NTILE * KSTEPS * 512 + 255) / 256, 256, 0, stream>>>(weights, wTf);
    kpconv_kernel<<<NPTS / MPTS, THREADS, 0, stream>>>(pos, feats, kpts, wTf, neighbors, out);
}